// Round 9
// baseline (284.955 us; speedup 1.0000x reference)
//
#include <hip/hip_runtime.h>
#include <hip/hip_fp16.h>

// ---------------------------------------------------------------------------
// GCN 3-layer forward on MI355X.
// detect edge layout -> deg -> dinv -> scan -> CSR fill -> W-split x3
//   -> [MFMA GEMM (bf16x3 split of f32) + dinv-scaled fp16 epilogue -> AGG] x3
// GEMM: no LDS/barriers. Wave tile 64 rows x 32 cols (MF=4, NF=2); block =
//       F/32 waves covering F cols; grid = (N+63)/64 (~3 waves/SIMD).
//       TRUE pipeline via sched_barrier(0) fences (r6-r8 post-mortem: without
//       fences the compiler sinks "prefetch" loads to their uses - VGPR=88
//       proved the A-ring never lived; and in-order vmcnt means B queued
//       behind A drains the A prefetch). Issue order per K-step:
//       [B(t+1)] fence [A(t+2)] fence [split(t) + MFMA(t)] -> B-wait is
//       vmcnt(24), drains nothing; A age ~2 iters covers HBM latency.
// AGG:  per-dst gather of fp16 H' rows; F=128 wave/node, F=64 half-wave/node.
//       y = dinv_d*(sum H'[s] + H'[d]) + b  (dinv folded at both ends).
// ---------------------------------------------------------------------------

typedef __attribute__((ext_vector_type(8))) short bf16x8;
typedef __attribute__((ext_vector_type(4))) float f32x4;
typedef unsigned short u16;
typedef unsigned int u32;

static inline size_t alignup(size_t v, size_t a) { return (v + a - 1) & ~(a - 1); }

// pack top-16 bits of two f32 bit patterns into one u32 (lo half from b0)
__device__ __forceinline__ u32 pack_hi16(u32 b0, u32 b1) {
    return __builtin_amdgcn_perm(b1, b0, 0x07060302u);
}

// --- edge dtype detect: if input is int64, every odd 32-bit word is 0 -------
__global__ void k_detect(const int* __restrict__ ei, int* __restrict__ flag) {
    int v = ei[2 * threadIdx.x + 1];
    unsigned long long b = __ballot(v != 0);
    if (threadIdx.x == 0) *flag = (b == 0ull) ? 1 : 0;   // 1 => int64 layout
}

__global__ void k_zero2(int* __restrict__ a, int* __restrict__ b, int n) {
    int i = blockIdx.x * blockDim.x + threadIdx.x;
    if (i < n) { a[i] = 0; b[i] = 0; }
}

__global__ void k_deg(const int* __restrict__ ei, int E,
                      const int* __restrict__ flag, int* __restrict__ deg) {
    int i = blockIdx.x * blockDim.x + threadIdx.x;
    if (i >= E) return;
    int is64 = *flag;
    int d = is64 ? ei[2 * (E + i)] : ei[E + i];
    atomicAdd(&deg[d], 1);
}

__global__ void k_dinv(const int* __restrict__ deg, float* __restrict__ dinv, int N) {
    int i = blockIdx.x * blockDim.x + threadIdx.x;
    if (i < N) dinv[i] = rsqrtf((float)deg[i] + 1.0f);
}

// --- 3-kernel exclusive scan over deg (256 elems/block) ---------------------
__global__ void k_scan1(const int* __restrict__ deg, int* __restrict__ offs,
                        int* __restrict__ bsums, int N) {
    __shared__ int s[256];
    int i = blockIdx.x * 256 + threadIdx.x;
    int v = (i < N) ? deg[i] : 0;
    s[threadIdx.x] = v;
    __syncthreads();
    for (int off = 1; off < 256; off <<= 1) {
        int t = (threadIdx.x >= off) ? s[threadIdx.x - off] : 0;
        __syncthreads();
        s[threadIdx.x] += t;
        __syncthreads();
    }
    if (i < N) offs[i] = s[threadIdx.x] - v;   // exclusive
    if (threadIdx.x == 255) bsums[blockIdx.x] = s[255];
}

__global__ void k_scan2(const int* __restrict__ bsums, int* __restrict__ boffs, int nb) {
    __shared__ int s[256];
    int i = threadIdx.x;
    int v = (i < nb) ? bsums[i] : 0;
    s[i] = v;
    __syncthreads();
    for (int off = 1; off < 256; off <<= 1) {
        int t = (i >= off) ? s[i - off] : 0;
        __syncthreads();
        s[i] += t;
        __syncthreads();
    }
    if (i < nb) boffs[i] = s[i] - v;
}

__global__ void k_scan3(int* __restrict__ offs, const int* __restrict__ boffs,
                        int N, int E) {
    int i = blockIdx.x * blockDim.x + threadIdx.x;
    if (i < N) offs[i] += boffs[i >> 8];
    if (i == 0) offs[N] = E;
}

__global__ void k_fill(const int* __restrict__ ei, int E,
                       const int* __restrict__ flag,
                       const int* __restrict__ offs, int* __restrict__ cnt,
                       int* __restrict__ csr) {
    int i = blockIdx.x * blockDim.x + threadIdx.x;
    if (i >= E) return;
    int is64 = *flag;
    int s = is64 ? ei[2 * i] : ei[i];
    int d = is64 ? ei[2 * (E + i)] : ei[E + i];
    int slot = offs[d] + atomicAdd(&cnt[d], 1);
    csr[slot] = s;
}

// --- W pre-split into fragment-ordered bf16 hi/lo ----------------------------
// slot s = ((t*4+g)*F + c) holds W[t*32+g*8+j][c], j=0..7, as 8 bf16 (16 B).
template <int K, int F>
__global__ void k_splitW(const float* __restrict__ W, u16* __restrict__ Wh,
                         u16* __restrict__ Wl) {
    int s = blockIdx.x * 256 + threadIdx.x;
    if (s >= K * F / 8) return;
    int c = s % F;
    int kb = (s / F) * 8;
    union { u32 u[4]; bf16x8 v; } hi, lo;
#pragma unroll
    for (int p = 0; p < 4; p++) {
        float x0 = W[(size_t)(kb + 2 * p) * F + c];
        float x1 = W[(size_t)(kb + 2 * p + 1) * F + c];
        u32 b0 = __float_as_uint(x0), b1 = __float_as_uint(x1);
        float l0 = x0 - __uint_as_float(b0 & 0xFFFF0000u);
        float l1 = x1 - __uint_as_float(b1 & 0xFFFF0000u);
        hi.u[p] = pack_hi16(b0, b1);
        lo.u[p] = pack_hi16(__float_as_uint(l0), __float_as_uint(l1));
    }
    *(bf16x8*)(Wh + (size_t)s * 8) = hi.v;
    *(bf16x8*)(Wl + (size_t)s * 8) = lo.v;
}

// --- MFMA GEMM: H'[N,F] = dinv_row * (X[N,K] @ W[K,F]), fp16 out -------------
// F/32 waves per block; wave tile 64 rows x 32 cols (MF=4, NF=2).
// Pipelined: B 1-deep, A 2-deep (3-slot ring), sched_barrier(0) issue fences.
template <int K, int F>
__global__ __launch_bounds__(2 * F) void k_gemm_mfma(
        const float* __restrict__ X,
        const u16* __restrict__ Wh, const u16* __restrict__ Wl,
        const float* __restrict__ dinv, __half* __restrict__ Hh, int N) {
    constexpr int MF = 4;
    constexpr int NF = 2;
    constexpr int NT = K / 32;         // K-steps
    const int tid = threadIdx.x;
    const int lane = tid & 63;
    const int wn = tid >> 6;           // 0..F/32-1 column slice
    const int lg = lane >> 4, li = lane & 15;
    const int row0 = blockIdx.x * 64;
    const int colbase = wn * 32;

    const float* xrow[MF];
#pragma unroll
    for (int m = 0; m < MF; m++) {
        int r = row0 + m * 16 + li;
        xrow[m] = X + (size_t)(r < N ? r : N - 1) * K;
    }

    f32x4 acc[MF][NF];
#pragma unroll
    for (int m = 0; m < MF; m++)
#pragma unroll
        for (int n = 0; n < NF; n++) acc[m][n] = (f32x4){0.f, 0.f, 0.f, 0.f};

    // prologue: B(0), A(0), A(1) (B first so its wait never drains A)
    bf16x8 bh[NF], bl[NF];
    {
        size_t slot0 = (size_t)lg * F + colbase + li;
#pragma unroll
        for (int n = 0; n < NF; n++) {
            bh[n] = *(const bf16x8*)(Wh + (slot0 + n * 16) * 8);
            bl[n] = *(const bf16x8*)(Wl + (slot0 + n * 16) * 8);
        }
    }
    __builtin_amdgcn_sched_barrier(0);
    float4 araw[3][MF][2];
#pragma unroll
    for (int m = 0; m < MF; m++) {
        const float* p = xrow[m] + lg * 8;
        araw[0][m][0] = *(const float4*)p;
        araw[0][m][1] = *(const float4*)(p + 4);
    }
    if (NT > 1) {
#pragma unroll
        for (int m = 0; m < MF; m++) {
            const float* p = xrow[m] + 32 + lg * 8;
            araw[1][m][0] = *(const float4*)p;
            araw[1][m][1] = *(const float4*)(p + 4);
        }
    }
    __builtin_amdgcn_sched_barrier(0);

#pragma unroll
    for (int t = 0; t < NT; t++) {
        // B(t+1) loads FIRST (so waiting for them later drains no A loads)
        bf16x8 bhn[NF], bln[NF];
        if (t + 1 < NT) {
            size_t slot1 = (size_t)((t + 1) * 4 + lg) * F + colbase + li;
#pragma unroll
            for (int n = 0; n < NF; n++) {
                bhn[n] = *(const bf16x8*)(Wh + (slot1 + n * 16) * 8);
                bln[n] = *(const bf16x8*)(Wl + (slot1 + n * 16) * 8);
            }
        }
        __builtin_amdgcn_sched_barrier(0);
        // A(t+2) prefetch into ring slot (static index: loop fully unrolled)
        if (t + 2 < NT) {
#pragma unroll
            for (int m = 0; m < MF; m++) {
                const float* p = xrow[m] + (t + 2) * 32 + lg * 8;
                araw[(t + 2) % 3][m][0] = *(const float4*)p;
                araw[(t + 2) % 3][m][1] = *(const float4*)(p + 4);
            }
        }
        __builtin_amdgcn_sched_barrier(0);
        // split A(t) -> hi/lo bf16x8 (loads issued 2 iterations ago)
        bf16x8 ah[MF], al[MF];
#pragma unroll
        for (int m = 0; m < MF; m++) {
            const float4& c0 = araw[t % 3][m][0];
            const float4& c1 = araw[t % 3][m][1];
            float xv[8] = {c0.x, c0.y, c0.z, c0.w, c1.x, c1.y, c1.z, c1.w};
            union { u32 u[4]; bf16x8 v; } hi, lo;
#pragma unroll
            for (int q = 0; q < 4; q++) {
                u32 b0 = __float_as_uint(xv[2 * q]);
                u32 b1 = __float_as_uint(xv[2 * q + 1]);
                float l0 = xv[2 * q]     - __uint_as_float(b0 & 0xFFFF0000u);
                float l1 = xv[2 * q + 1] - __uint_as_float(b1 & 0xFFFF0000u);
                hi.u[q] = pack_hi16(b0, b1);
                lo.u[q] = pack_hi16(__float_as_uint(l0), __float_as_uint(l1));
            }
            ah[m] = hi.v;
            al[m] = lo.v;
        }
        // 3-product accumulation: xh*wh + xh*wl + xl*wh (B from last iter)
#pragma unroll
        for (int m = 0; m < MF; m++)
#pragma unroll
            for (int n = 0; n < NF; n++) {
                acc[m][n] = __builtin_amdgcn_mfma_f32_16x16x32_bf16(ah[m], bh[n], acc[m][n], 0, 0, 0);
                acc[m][n] = __builtin_amdgcn_mfma_f32_16x16x32_bf16(ah[m], bl[n], acc[m][n], 0, 0, 0);
                acc[m][n] = __builtin_amdgcn_mfma_f32_16x16x32_bf16(al[m], bh[n], acc[m][n], 0, 0, 0);
            }
        // rotate B buffers (unrolled loop renames registers)
#pragma unroll
        for (int n = 0; n < NF; n++) {
            bh[n] = bhn[n];
            bl[n] = bln[n];
        }
    }

    // C/D layout: col = lane&15, row = (lane>>4)*4 + reg (m89-verified)
    // Epilogue folds dinv[row] and converts to fp16.
#pragma unroll
    for (int m = 0; m < MF; m++) {
        int rb = row0 + m * 16 + lg * 4;
#pragma unroll
        for (int r = 0; r < 4; r++) {
            int gr = rb + r;
            if (gr >= N) continue;
            float di = dinv[gr];
#pragma unroll
            for (int n = 0; n < NF; n++) {
                int col = colbase + n * 16 + li;
                Hh[(size_t)gr * F + col] = __float2half(acc[m][n][r] * di);
            }
        }
    }
}

// --- aggregation, F=128, fp16 H' in, f32 out ---------------------------------
// y = act(dinv_d * (sum_s H'[s] + H'[d]) + b); one wave per node; 4-edge unroll.
template <bool RELU>
__global__ __launch_bounds__(256) void k_agg128(const __half* __restrict__ Hh,
                                                const int* __restrict__ offs,
                                                const int* __restrict__ csr,
                                                const float* __restrict__ dinv,
                                                const float* __restrict__ bias,
                                                float* __restrict__ Y, int N) {
    int node = blockIdx.x * 4 + (threadIdx.x >> 6);
    int lane = threadIdx.x & 63;
    if (node >= N) return;
    const __half2* H2 = (const __half2*)Hh;   // row = 64 half2
    float ax = 0.f, ay = 0.f;
    int o0 = offs[node], o1 = offs[node + 1];
    int e = o0;
    for (; e + 4 <= o1; e += 4) {
        int s0 = csr[e], s1 = csr[e + 1], s2 = csr[e + 2], s3 = csr[e + 3];
        __half2 v0 = H2[(size_t)s0 * 64 + lane];
        __half2 v1 = H2[(size_t)s1 * 64 + lane];
        __half2 v2 = H2[(size_t)s2 * 64 + lane];
        __half2 v3 = H2[(size_t)s3 * 64 + lane];
        float2 f0 = __half22float2(v0), f1 = __half22float2(v1);
        float2 f2 = __half22float2(v2), f3 = __half22float2(v3);
        ax += (f0.x + f1.x) + (f2.x + f3.x);
        ay += (f0.y + f1.y) + (f2.y + f3.y);
    }
    for (; e < o1; ++e) {
        float2 f0 = __half22float2(H2[(size_t)csr[e] * 64 + lane]);
        ax += f0.x; ay += f0.y;
    }
    float2 fs = __half22float2(H2[(size_t)node * 64 + lane]);
    float di = dinv[node];
    float2 bv = ((const float2*)bias)[lane];
    float vx = di * (ax + fs.x) + bv.x;
    float vy = di * (ay + fs.y) + bv.y;
    if (RELU) { vx = vx > 0.f ? vx : 0.2f * vx; vy = vy > 0.f ? vy : 0.2f * vy; }
    ((float2*)Y)[(size_t)node * 64 + lane] = make_float2(vx, vy);
}

// --- aggregation, F=64, fp16 H' in, f32 out ----------------------------------
// Half-wave (32 lanes) per node: fp16 row = 128 B = 32 x half2. 8 nodes/block.
template <bool RELU>
__global__ __launch_bounds__(256) void k_agg64(const __half* __restrict__ Hh,
                                               const int* __restrict__ offs,
                                               const int* __restrict__ csr,
                                               const float* __restrict__ dinv,
                                               const float* __restrict__ bias,
                                               float* __restrict__ Y, int N) {
    int node = blockIdx.x * 8 + (threadIdx.x >> 5);
    int lane = threadIdx.x & 31;
    if (node >= N) return;
    const __half2* H2 = (const __half2*)Hh;   // row = 32 half2
    float ax = 0.f, ay = 0.f;
    int o0 = offs[node], o1 = offs[node + 1];
    int e = o0;
    for (; e + 4 <= o1; e += 4) {
        int s0 = csr[e], s1 = csr[e + 1], s2 = csr[e + 2], s3 = csr[e + 3];
        float2 f0 = __half22float2(H2[(size_t)s0 * 32 + lane]);
        float2 f1 = __half22float2(H2[(size_t)s1 * 32 + lane]);
        float2 f2 = __half22float2(H2[(size_t)s2 * 32 + lane]);
        float2 f3 = __half22float2(H2[(size_t)s3 * 32 + lane]);
        ax += (f0.x + f1.x) + (f2.x + f3.x);
        ay += (f0.y + f1.y) + (f2.y + f3.y);
    }
    for (; e < o1; ++e) {
        float2 f0 = __half22float2(H2[(size_t)csr[e] * 32 + lane]);
        ax += f0.x; ay += f0.y;
    }
    float2 fs = __half22float2(H2[(size_t)node * 32 + lane]);
    float di = dinv[node];
    float2 bv = ((const float2*)bias)[lane];
    float vx = di * (ax + fs.x) + bv.x;
    float vy = di * (ay + fs.y) + bv.y;
    if (RELU) { vx = vx > 0.f ? vx : 0.2f * vx; vy = vy > 0.f ? vy : 0.2f * vy; }
    ((float2*)Y)[(size_t)node * 32 + lane] = make_float2(vx, vy);
}

extern "C" void kernel_launch(void* const* d_in, const int* in_sizes, int n_in,
                              void* d_out, int out_size, void* d_ws, size_t ws_size,
                              hipStream_t stream) {
    const float* x  = (const float*)d_in[0];
    const int*   ei = (const int*)d_in[1];
    const float* W1 = (const float*)d_in[2];
    const float* b1 = (const float*)d_in[3];
    const float* W2 = (const float*)d_in[4];
    const float* b2 = (const float*)d_in[5];
    const float* W3 = (const float*)d_in[6];
    const float* b3 = (const float*)d_in[7];

    const int N = in_sizes[0] / 512;
    const int E = in_sizes[1] / 2;
    const int nb = (N + 255) / 256;

    char* w = (char*)d_ws;
    auto take = [&](size_t bytes) -> char* {
        char* p = w;
        w += alignup(bytes, 256);
        return p;
    };
    int*    flag  = (int*)take(256);
    int*    deg   = (int*)take((size_t)N * 4);
    int*    cnt   = (int*)take((size_t)N * 4);
    int*    offs  = (int*)take((size_t)(N + 1) * 4);
    int*    bsums = (int*)take((size_t)nb * 4);
    int*    boffs = (int*)take((size_t)nb * 4);
    int*    csr   = (int*)take((size_t)E * 4);
    float*  dinv  = (float*)take((size_t)N * 4);
    __half* bufA  = (__half*)take((size_t)N * 128 * 2);   // H' fp16
    float*  bufB  = (float*)take((size_t)N * 128 * 4);    // agg out f32
    u16*    w1h   = (u16*)take((size_t)512 * 128 * 2);
    u16*    w1l   = (u16*)take((size_t)512 * 128 * 2);
    u16*    w2h   = (u16*)take((size_t)128 * 64 * 2);
    u16*    w2l   = (u16*)take((size_t)128 * 64 * 2);
    u16*    w3h   = (u16*)take((size_t)64 * 64 * 2);
    u16*    w3l   = (u16*)take((size_t)64 * 64 * 2);

    const int TB = 256;
    // preprocessing
    k_detect<<<1, 64, 0, stream>>>(ei, flag);
    k_zero2<<<(N + TB - 1) / TB, TB, 0, stream>>>(deg, cnt, N);
    k_deg<<<(E + TB - 1) / TB, TB, 0, stream>>>(ei, E, flag, deg);
    k_dinv<<<(N + TB - 1) / TB, TB, 0, stream>>>(deg, dinv, N);
    k_scan1<<<nb, 256, 0, stream>>>(deg, offs, bsums, N);
    k_scan2<<<1, 256, 0, stream>>>(bsums, boffs, nb);
    k_scan3<<<(N + TB - 1) / TB, TB, 0, stream>>>(offs, boffs, N, E);
    k_fill<<<(E + TB - 1) / TB, TB, 0, stream>>>(ei, E, flag, offs, cnt, csr);
    // W splits
    k_splitW<512, 128><<<(512 * 128 / 8 + 255) / 256, 256, 0, stream>>>(W1, w1h, w1l);
    k_splitW<128, 64><<<(128 * 64 / 8 + 255) / 256, 256, 0, stream>>>(W2, w2h, w2l);
    k_splitW<64, 64><<<(64 * 64 / 8 + 255) / 256, 256, 0, stream>>>(W3, w3h, w3l);

    const int gemm_grid = (N + 63) / 64;
    // layer 1
    k_gemm_mfma<512, 128><<<gemm_grid, 256, 0, stream>>>(x, w1h, w1l, dinv, bufA, N);
    k_agg128<true><<<(N + 3) / 4, 256, 0, stream>>>(bufA, offs, csr, dinv, b1, bufB, N);
    // layer 2
    k_gemm_mfma<128, 64><<<gemm_grid, 128, 0, stream>>>(bufB, w2h, w2l, dinv, bufA, N);
    k_agg64<true><<<(N + 7) / 8, 256, 0, stream>>>(bufA, offs, csr, dinv, b2, bufB, N);
    // layer 3 (no relu), write straight to output
    k_gemm_mfma<64, 64><<<gemm_grid, 128, 0, stream>>>(bufB, w3h, w3l, dinv, bufA, N);
    k_agg64<false><<<(N + 7) / 8, 256, 0, stream>>>(bufA, offs, csr, dinv, b3,
                                                    (float*)d_out, N);
}

// Round 10
// 240.675 us; speedup vs baseline: 1.1840x; 1.1840x over previous
//
#include <hip/hip_runtime.h>
#include <hip/hip_fp16.h>

// ---------------------------------------------------------------------------
// GCN 3-layer forward on MI355X.
// detect edge layout -> deg -> dinv -> scan -> CSR fill -> W-split x3
//   -> [MFMA GEMM (bf16x3 split of f32) + dinv-scaled fp16 epilogue -> AGG] x3
// GEMM (r10): LDS-staged A via global_load_lds (2-phase pipeline).
//   Block = 128 rows x F cols, 256 thr = 4 waves (2x2), wave tile 64x64/64x32.
//   Per K-step: [B(t) loads] SB [stage A(t+1): 16B DMA x4/thr, swizzled src]
//   [ds_read A(t) b128 + split + MFMA] __syncthreads.
//   r6-r9 lesson: register prefetch is DEAD (compiler sinks pure loads; vmcnt
//   in-order drains). global_load_lds can't be sunk; barrier = the only drain.
//   A tile [128][32] f32, chunk-swizzle c^=(row&7) on SOURCE addr (linear LDS
//   dest per m104; swizzle both-sides rule m228c).
// AGG:  per-dst gather of fp16 H' rows; F=128 wave/node, F=64 half-wave/node.
//       y = dinv_d*(sum H'[s] + H'[d]) + b  (dinv folded at both ends).
// ---------------------------------------------------------------------------

typedef __attribute__((ext_vector_type(8))) short bf16x8;
typedef __attribute__((ext_vector_type(4))) float f32x4;
typedef unsigned short u16;
typedef unsigned int u32;

static inline size_t alignup(size_t v, size_t a) { return (v + a - 1) & ~(a - 1); }

// pack top-16 bits of two f32 bit patterns into one u32 (lo half from b0)
__device__ __forceinline__ u32 pack_hi16(u32 b0, u32 b1) {
    return __builtin_amdgcn_perm(b1, b0, 0x07060302u);
}

// --- edge dtype detect: if input is int64, every odd 32-bit word is 0 -------
__global__ void k_detect(const int* __restrict__ ei, int* __restrict__ flag) {
    int v = ei[2 * threadIdx.x + 1];
    unsigned long long b = __ballot(v != 0);
    if (threadIdx.x == 0) *flag = (b == 0ull) ? 1 : 0;   // 1 => int64 layout
}

__global__ void k_zero2(int* __restrict__ a, int* __restrict__ b, int n) {
    int i = blockIdx.x * blockDim.x + threadIdx.x;
    if (i < n) { a[i] = 0; b[i] = 0; }
}

__global__ void k_deg(const int* __restrict__ ei, int E,
                      const int* __restrict__ flag, int* __restrict__ deg) {
    int i = blockIdx.x * blockDim.x + threadIdx.x;
    if (i >= E) return;
    int is64 = *flag;
    int d = is64 ? ei[2 * (E + i)] : ei[E + i];
    atomicAdd(&deg[d], 1);
}

__global__ void k_dinv(const int* __restrict__ deg, float* __restrict__ dinv, int N) {
    int i = blockIdx.x * blockDim.x + threadIdx.x;
    if (i < N) dinv[i] = rsqrtf((float)deg[i] + 1.0f);
}

// --- 3-kernel exclusive scan over deg (256 elems/block) ---------------------
__global__ void k_scan1(const int* __restrict__ deg, int* __restrict__ offs,
                        int* __restrict__ bsums, int N) {
    __shared__ int s[256];
    int i = blockIdx.x * 256 + threadIdx.x;
    int v = (i < N) ? deg[i] : 0;
    s[threadIdx.x] = v;
    __syncthreads();
    for (int off = 1; off < 256; off <<= 1) {
        int t = (threadIdx.x >= off) ? s[threadIdx.x - off] : 0;
        __syncthreads();
        s[threadIdx.x] += t;
        __syncthreads();
    }
    if (i < N) offs[i] = s[threadIdx.x] - v;   // exclusive
    if (threadIdx.x == 255) bsums[blockIdx.x] = s[255];
}

__global__ void k_scan2(const int* __restrict__ bsums, int* __restrict__ boffs, int nb) {
    __shared__ int s[256];
    int i = threadIdx.x;
    int v = (i < nb) ? bsums[i] : 0;
    s[i] = v;
    __syncthreads();
    for (int off = 1; off < 256; off <<= 1) {
        int t = (i >= off) ? s[i - off] : 0;
        __syncthreads();
        s[i] += t;
        __syncthreads();
    }
    if (i < nb) boffs[i] = s[i] - v;
}

__global__ void k_scan3(int* __restrict__ offs, const int* __restrict__ boffs,
                        int N, int E) {
    int i = blockIdx.x * blockDim.x + threadIdx.x;
    if (i < N) offs[i] += boffs[i >> 8];
    if (i == 0) offs[N] = E;
}

__global__ void k_fill(const int* __restrict__ ei, int E,
                       const int* __restrict__ flag,
                       const int* __restrict__ offs, int* __restrict__ cnt,
                       int* __restrict__ csr) {
    int i = blockIdx.x * blockDim.x + threadIdx.x;
    if (i >= E) return;
    int is64 = *flag;
    int s = is64 ? ei[2 * i] : ei[i];
    int d = is64 ? ei[2 * (E + i)] : ei[E + i];
    int slot = offs[d] + atomicAdd(&cnt[d], 1);
    csr[slot] = s;
}

// --- W pre-split into fragment-ordered bf16 hi/lo ----------------------------
// slot s = ((t*4+g)*F + c) holds W[t*32+g*8+j][c], j=0..7, as 8 bf16 (16 B).
template <int K, int F>
__global__ void k_splitW(const float* __restrict__ W, u16* __restrict__ Wh,
                         u16* __restrict__ Wl) {
    int s = blockIdx.x * 256 + threadIdx.x;
    if (s >= K * F / 8) return;
    int c = s % F;
    int kb = (s / F) * 8;
    union { u32 u[4]; bf16x8 v; } hi, lo;
#pragma unroll
    for (int p = 0; p < 4; p++) {
        float x0 = W[(size_t)(kb + 2 * p) * F + c];
        float x1 = W[(size_t)(kb + 2 * p + 1) * F + c];
        u32 b0 = __float_as_uint(x0), b1 = __float_as_uint(x1);
        float l0 = x0 - __uint_as_float(b0 & 0xFFFF0000u);
        float l1 = x1 - __uint_as_float(b1 & 0xFFFF0000u);
        hi.u[p] = pack_hi16(b0, b1);
        lo.u[p] = pack_hi16(__float_as_uint(l0), __float_as_uint(l1));
    }
    *(bf16x8*)(Wh + (size_t)s * 8) = hi.v;
    *(bf16x8*)(Wl + (size_t)s * 8) = lo.v;
}

// --- MFMA GEMM: H'[N,F] = dinv_row * (X[N,K] @ W[K,F]), fp16 out -------------
// 256 thr = 4 waves (2 row-halves x 2 col-halves); block tile 128 rows x F.
// A K-tile [128][32] f32 double-buffered in LDS via global_load_lds (src
// chunk-swizzled c^=(row&7)); B direct global (L2-resident W splits).
template <int K, int F>
__global__ __launch_bounds__(256) void k_gemm_mfma(
        const float* __restrict__ X,
        const u16* __restrict__ Wh, const u16* __restrict__ Wl,
        const float* __restrict__ dinv, __half* __restrict__ Hh, int N) {
    constexpr int MF = 4;
    constexpr int NF = F / 32;         // 4 for F=128, 2 for F=64
    constexpr int NT = K / 32;         // K-steps
    __shared__ float4 smemA[2][1024];  // 2 x 16 KB: [row][chunk] swizzled

    const int tid = threadIdx.x;
    const int lane = tid & 63;
    const int w = tid >> 6;
    const int wm = (w >> 1) * 64;      // wave row-half
    const int colbase = (w & 1) * (NF * 16);
    const int lg = lane >> 4, li = lane & 15;
    const int row0 = blockIdx.x * 128;

    // stage K-tile t into buffer b: lds chunk c_lin=(j*256+tid) holds
    // X[row0 + c_lin>>3][t*32 + ((c_lin&7)^(row&7))*4 ..+3]
    auto stage = [&](int b, int t) {
#pragma unroll
        for (int j = 0; j < 4; j++) {
            int c_lin = j * 256 + tid;
            int row = c_lin >> 3, c = c_lin & 7;
            int rg = row0 + row;
            if (rg >= N) rg = N - 1;
            int cs = c ^ (row & 7);
            const float* g = X + (size_t)rg * K + t * 32 + cs * 4;
            // dest: wave-uniform base + lane*16 (m104) => base per (j, wave)
            char* l = (char*)&smemA[b][0] + j * 4096 + w * 1024;
            __builtin_amdgcn_global_load_lds(
                (const __attribute__((address_space(1))) void*)g,
                (__attribute__((address_space(3))) void*)l, 16, 0, 0);
        }
    };

    f32x4 acc[MF][NF];
#pragma unroll
    for (int m = 0; m < MF; m++)
#pragma unroll
        for (int n = 0; n < NF; n++) acc[m][n] = (f32x4){0.f, 0.f, 0.f, 0.f};

    stage(0, 0);
    __syncthreads();

    for (int t = 0; t < NT; t++) {
        const int b = t & 1;
        // B(t) loads FIRST (their vmcnt wait must not drain the stage DMA)
        bf16x8 bh[NF], bl[NF];
        size_t slot0 = (size_t)(t * 4 + lg) * F + colbase + li;
#pragma unroll
        for (int n = 0; n < NF; n++) {
            bh[n] = *(const bf16x8*)(Wh + (slot0 + n * 16) * 8);
            bl[n] = *(const bf16x8*)(Wl + (slot0 + n * 16) * 8);
        }
        __builtin_amdgcn_sched_barrier(0);   // keep B issued before stage
        if (t + 1 < NT) stage(b ^ 1, t + 1); // async DMA, drained at barrier
        // A(t) fragments from LDS (swizzled b128 reads) -> split -> MFMA
        const float4* lt = &smemA[b][0];
        bf16x8 ah[MF], al[MF];
#pragma unroll
        for (int m = 0; m < MF; m++) {
            int row = wm + m * 16 + li;
            int base = row * 8, sw = row & 7;
            float4 c0 = lt[base + ((2 * lg) ^ sw)];
            float4 c1 = lt[base + ((2 * lg + 1) ^ sw)];
            float xv[8] = {c0.x, c0.y, c0.z, c0.w, c1.x, c1.y, c1.z, c1.w};
            union { u32 u[4]; bf16x8 v; } hi, lo;
#pragma unroll
            for (int q = 0; q < 4; q++) {
                u32 b0 = __float_as_uint(xv[2 * q]);
                u32 b1 = __float_as_uint(xv[2 * q + 1]);
                float l0 = xv[2 * q]     - __uint_as_float(b0 & 0xFFFF0000u);
                float l1 = xv[2 * q + 1] - __uint_as_float(b1 & 0xFFFF0000u);
                hi.u[q] = pack_hi16(b0, b1);
                lo.u[q] = pack_hi16(__float_as_uint(l0), __float_as_uint(l1));
            }
            ah[m] = hi.v;
            al[m] = lo.v;
        }
        // 3-product accumulation: xh*wh + xh*wl + xl*wh
#pragma unroll
        for (int m = 0; m < MF; m++)
#pragma unroll
            for (int n = 0; n < NF; n++) {
                acc[m][n] = __builtin_amdgcn_mfma_f32_16x16x32_bf16(ah[m], bh[n], acc[m][n], 0, 0, 0);
                acc[m][n] = __builtin_amdgcn_mfma_f32_16x16x32_bf16(ah[m], bl[n], acc[m][n], 0, 0, 0);
                acc[m][n] = __builtin_amdgcn_mfma_f32_16x16x32_bf16(al[m], bh[n], acc[m][n], 0, 0, 0);
            }
        __syncthreads();   // drains stage(t+1) DMA + release buf b for t+2
    }

    // C/D layout: col = lane&15, row = (lane>>4)*4 + reg (m89-verified)
    // Epilogue folds dinv[row] and converts to fp16.
#pragma unroll
    for (int m = 0; m < MF; m++) {
        int rb = row0 + wm + m * 16 + lg * 4;
#pragma unroll
        for (int r = 0; r < 4; r++) {
            int gr = rb + r;
            if (gr >= N) continue;
            float di = dinv[gr];
#pragma unroll
            for (int n = 0; n < NF; n++) {
                int col = colbase + n * 16 + li;
                Hh[(size_t)gr * F + col] = __float2half(acc[m][n][r] * di);
            }
        }
    }
}

// --- aggregation, F=128, fp16 H' in, f32 out ---------------------------------
// y = act(dinv_d * (sum_s H'[s] + H'[d]) + b); one wave per node; 4-edge unroll.
template <bool RELU>
__global__ __launch_bounds__(256) void k_agg128(const __half* __restrict__ Hh,
                                                const int* __restrict__ offs,
                                                const int* __restrict__ csr,
                                                const float* __restrict__ dinv,
                                                const float* __restrict__ bias,
                                                float* __restrict__ Y, int N) {
    int node = blockIdx.x * 4 + (threadIdx.x >> 6);
    int lane = threadIdx.x & 63;
    if (node >= N) return;
    const __half2* H2 = (const __half2*)Hh;   // row = 64 half2
    float ax = 0.f, ay = 0.f;
    int o0 = offs[node], o1 = offs[node + 1];
    int e = o0;
    for (; e + 4 <= o1; e += 4) {
        int s0 = csr[e], s1 = csr[e + 1], s2 = csr[e + 2], s3 = csr[e + 3];
        __half2 v0 = H2[(size_t)s0 * 64 + lane];
        __half2 v1 = H2[(size_t)s1 * 64 + lane];
        __half2 v2 = H2[(size_t)s2 * 64 + lane];
        __half2 v3 = H2[(size_t)s3 * 64 + lane];
        float2 f0 = __half22float2(v0), f1 = __half22float2(v1);
        float2 f2 = __half22float2(v2), f3 = __half22float2(v3);
        ax += (f0.x + f1.x) + (f2.x + f3.x);
        ay += (f0.y + f1.y) + (f2.y + f3.y);
    }
    for (; e < o1; ++e) {
        float2 f0 = __half22float2(H2[(size_t)csr[e] * 64 + lane]);
        ax += f0.x; ay += f0.y;
    }
    float2 fs = __half22float2(H2[(size_t)node * 64 + lane]);
    float di = dinv[node];
    float2 bv = ((const float2*)bias)[lane];
    float vx = di * (ax + fs.x) + bv.x;
    float vy = di * (ay + fs.y) + bv.y;
    if (RELU) { vx = vx > 0.f ? vx : 0.2f * vx; vy = vy > 0.f ? vy : 0.2f * vy; }
    ((float2*)Y)[(size_t)node * 64 + lane] = make_float2(vx, vy);
}

// --- aggregation, F=64, fp16 H' in, f32 out ----------------------------------
// Half-wave (32 lanes) per node: fp16 row = 128 B = 32 x half2. 8 nodes/block.
template <bool RELU>
__global__ __launch_bounds__(256) void k_agg64(const __half* __restrict__ Hh,
                                               const int* __restrict__ offs,
                                               const int* __restrict__ csr,
                                               const float* __restrict__ dinv,
                                               const float* __restrict__ bias,
                                               float* __restrict__ Y, int N) {
    int node = blockIdx.x * 8 + (threadIdx.x >> 5);
    int lane = threadIdx.x & 31;
    if (node >= N) return;
    const __half2* H2 = (const __half2*)Hh;   // row = 32 half2
    float ax = 0.f, ay = 0.f;
    int o0 = offs[node], o1 = offs[node + 1];
    int e = o0;
    for (; e + 4 <= o1; e += 4) {
        int s0 = csr[e], s1 = csr[e + 1], s2 = csr[e + 2], s3 = csr[e + 3];
        float2 f0 = __half22float2(H2[(size_t)s0 * 32 + lane]);
        float2 f1 = __half22float2(H2[(size_t)s1 * 32 + lane]);
        float2 f2 = __half22float2(H2[(size_t)s2 * 32 + lane]);
        float2 f3 = __half22float2(H2[(size_t)s3 * 32 + lane]);
        ax += (f0.x + f1.x) + (f2.x + f3.x);
        ay += (f0.y + f1.y) + (f2.y + f3.y);
    }
    for (; e < o1; ++e) {
        float2 f0 = __half22float2(H2[(size_t)csr[e] * 32 + lane]);
        ax += f0.x; ay += f0.y;
    }
    float2 fs = __half22float2(H2[(size_t)node * 32 + lane]);
    float di = dinv[node];
    float2 bv = ((const float2*)bias)[lane];
    float vx = di * (ax + fs.x) + bv.x;
    float vy = di * (ay + fs.y) + bv.y;
    if (RELU) { vx = vx > 0.f ? vx : 0.2f * vx; vy = vy > 0.f ? vy : 0.2f * vy; }
    ((float2*)Y)[(size_t)node * 32 + lane] = make_float2(vx, vy);
}

extern "C" void kernel_launch(void* const* d_in, const int* in_sizes, int n_in,
                              void* d_out, int out_size, void* d_ws, size_t ws_size,
                              hipStream_t stream) {
    const float* x  = (const float*)d_in[0];
    const int*   ei = (const int*)d_in[1];
    const float* W1 = (const float*)d_in[2];
    const float* b1 = (const float*)d_in[3];
    const float* W2 = (const float*)d_in[4];
    const float* b2 = (const float*)d_in[5];
    const float* W3 = (const float*)d_in[6];
    const float* b3 = (const float*)d_in[7];

    const int N = in_sizes[0] / 512;
    const int E = in_sizes[1] / 2;
    const int nb = (N + 255) / 256;

    char* w = (char*)d_ws;
    auto take = [&](size_t bytes) -> char* {
        char* p = w;
        w += alignup(bytes, 256);
        return p;
    };
    int*    flag  = (int*)take(256);
    int*    deg   = (int*)take((size_t)N * 4);
    int*    cnt   = (int*)take((size_t)N * 4);
    int*    offs  = (int*)take((size_t)(N + 1) * 4);
    int*    bsums = (int*)take((size_t)nb * 4);
    int*    boffs = (int*)take((size_t)nb * 4);
    int*    csr   = (int*)take((size_t)E * 4);
    float*  dinv  = (float*)take((size_t)N * 4);
    __half* bufA  = (__half*)take((size_t)N * 128 * 2);   // H' fp16
    float*  bufB  = (float*)take((size_t)N * 128 * 4);    // agg out f32
    u16*    w1h   = (u16*)take((size_t)512 * 128 * 2);
    u16*    w1l   = (u16*)take((size_t)512 * 128 * 2);
    u16*    w2h   = (u16*)take((size_t)128 * 64 * 2);
    u16*    w2l   = (u16*)take((size_t)128 * 64 * 2);
    u16*    w3h   = (u16*)take((size_t)64 * 64 * 2);
    u16*    w3l   = (u16*)take((size_t)64 * 64 * 2);

    const int TB = 256;
    // preprocessing
    k_detect<<<1, 64, 0, stream>>>(ei, flag);
    k_zero2<<<(N + TB - 1) / TB, TB, 0, stream>>>(deg, cnt, N);
    k_deg<<<(E + TB - 1) / TB, TB, 0, stream>>>(ei, E, flag, deg);
    k_dinv<<<(N + TB - 1) / TB, TB, 0, stream>>>(deg, dinv, N);
    k_scan1<<<nb, 256, 0, stream>>>(deg, offs, bsums, N);
    k_scan2<<<1, 256, 0, stream>>>(bsums, boffs, nb);
    k_scan3<<<(N + TB - 1) / TB, TB, 0, stream>>>(offs, boffs, N, E);
    k_fill<<<(E + TB - 1) / TB, TB, 0, stream>>>(ei, E, flag, offs, cnt, csr);
    // W splits
    k_splitW<512, 128><<<(512 * 128 / 8 + 255) / 256, 256, 0, stream>>>(W1, w1h, w1l);
    k_splitW<128, 64><<<(128 * 64 / 8 + 255) / 256, 256, 0, stream>>>(W2, w2h, w2l);
    k_splitW<64, 64><<<(64 * 64 / 8 + 255) / 256, 256, 0, stream>>>(W3, w3h, w3l);

    const int gemm_grid = (N + 127) / 128;
    // layer 1
    k_gemm_mfma<512, 128><<<gemm_grid, 256, 0, stream>>>(x, w1h, w1l, dinv, bufA, N);
    k_agg128<true><<<(N + 3) / 4, 256, 0, stream>>>(bufA, offs, csr, dinv, b1, bufB, N);
    // layer 2
    k_gemm_mfma<128, 64><<<gemm_grid, 256, 0, stream>>>(bufB, w2h, w2l, dinv, bufA, N);
    k_agg64<true><<<(N + 7) / 8, 256, 0, stream>>>(bufA, offs, csr, dinv, b2, bufB, N);
    // layer 3 (no relu), write straight to output
    k_gemm_mfma<64, 64><<<gemm_grid, 256, 0, stream>>>(bufB, w3h, w3l, dinv, bufA, N);
    k_agg64<false><<<(N + 7) / 8, 256, 0, stream>>>(bufA, offs, csr, dinv, b3,
                                                    (float*)d_out, N);
}

// Round 11
// 235.235 us; speedup vs baseline: 1.2114x; 1.0231x over previous
//
#include <hip/hip_runtime.h>
#include <hip/hip_fp16.h>

// ---------------------------------------------------------------------------
// GCN 3-layer forward on MI355X.  (r11: balance + launch fusion)
// init(zero deg + detect) -> deg -> scan1(+dinv) -> scan23 -> fill(countdown)
//   -> splitW_all -> [MFMA GEMM (bf16x3, LDS-staged A) -> AGG] x3   (12 launches)
// GEMM: 64-row x F blocks, 2 waves (col halves), per-wave tile 64x64 (F=128)
//       / 64x32 (F=64). A K-tile [64][32] f32 double-buffered in LDS via
//       global_load_lds (src chunk-swizzled c^=(row&7), linear LDS dest);
//       B direct global (L2-resident W splits). Grid 782 = 3.05 blocks/CU
//       (r10 had 391 = 1.53/CU -> ~35% tail imbalance).
// AGG:  per-dst gather of fp16 H' rows; F=128 wave/node, F=64 half-wave/node.
//       y = dinv_d*(sum H'[s] + H'[d]) + b  (dinv folded at both ends).
// ---------------------------------------------------------------------------

typedef __attribute__((ext_vector_type(8))) short bf16x8;
typedef __attribute__((ext_vector_type(4))) float f32x4;
typedef unsigned short u16;
typedef unsigned int u32;

static inline size_t alignup(size_t v, size_t a) { return (v + a - 1) & ~(a - 1); }

// pack top-16 bits of two f32 bit patterns into one u32 (lo half from b0)
__device__ __forceinline__ u32 pack_hi16(u32 b0, u32 b1) {
    return __builtin_amdgcn_perm(b1, b0, 0x07060302u);
}

// --- init: zero deg; block 0 wave 0 detects int64-vs-int32 edge layout ------
__global__ void k_init(const int* __restrict__ ei, int* __restrict__ flag,
                       int* __restrict__ deg, int N) {
    int i = blockIdx.x * blockDim.x + threadIdx.x;
    if (i < N) deg[i] = 0;
    if (blockIdx.x == 0 && threadIdx.x < 64) {
        int v = ei[2 * threadIdx.x + 1];          // high word if int64
        unsigned long long b = __ballot(v != 0);
        if (threadIdx.x == 0) *flag = (b == 0ull) ? 1 : 0;
    }
}

__global__ void k_deg(const int* __restrict__ ei, int E,
                      const int* __restrict__ flag, int* __restrict__ deg) {
    int i = blockIdx.x * blockDim.x + threadIdx.x;
    if (i >= E) return;
    int is64 = *flag;
    int d = is64 ? ei[2 * (E + i)] : ei[E + i];
    atomicAdd(&deg[d], 1);
}

// --- scan stage 1: per-256-block exclusive scan of deg; also writes dinv ----
__global__ void k_scan1(const int* __restrict__ deg, int* __restrict__ offs,
                        int* __restrict__ bsums, float* __restrict__ dinv, int N) {
    __shared__ int s[256];
    int i = blockIdx.x * 256 + threadIdx.x;
    int v = (i < N) ? deg[i] : 0;
    if (i < N) dinv[i] = rsqrtf((float)v + 1.0f);
    s[threadIdx.x] = v;
    __syncthreads();
    for (int off = 1; off < 256; off <<= 1) {
        int t = (threadIdx.x >= off) ? s[threadIdx.x - off] : 0;
        __syncthreads();
        s[threadIdx.x] += t;
        __syncthreads();
    }
    if (i < N) offs[i] = s[threadIdx.x] - v;   // exclusive
    if (threadIdx.x == 255) bsums[blockIdx.x] = s[255];
}

// --- scan stages 2+3 fused: each block redundantly scans bsums (nb<=256) ----
__global__ void k_scan23(int* __restrict__ offs, const int* __restrict__ bsums,
                         int nb, int N, int E) {
    __shared__ int s[256];
    int tid = threadIdx.x;
    s[tid] = (tid < nb) ? bsums[tid] : 0;
    __syncthreads();
    for (int off = 1; off < 256; off <<= 1) {
        int t = (tid >= off) ? s[tid - off] : 0;
        __syncthreads();
        s[tid] += t;                 // inclusive scan
        __syncthreads();
    }
    int boff = (blockIdx.x > 0) ? s[blockIdx.x - 1] : 0;
    int i = blockIdx.x * 256 + tid;
    if (i < N) offs[i] += boff;
    if (i == 0) offs[N] = E;
}

// --- CSR fill via countdown on deg (no cnt array): slot = offs+old-1 --------
__global__ void k_fill(const int* __restrict__ ei, int E,
                       const int* __restrict__ flag,
                       const int* __restrict__ offs, int* __restrict__ deg,
                       int* __restrict__ csr) {
    int i = blockIdx.x * blockDim.x + threadIdx.x;
    if (i >= E) return;
    int is64 = *flag;
    int s = is64 ? ei[2 * i] : ei[i];
    int d = is64 ? ei[2 * (E + i)] : ei[E + i];
    int slot = offs[d] + atomicSub(&deg[d], 1) - 1;
    csr[slot] = s;
}

// --- W pre-split into fragment-ordered bf16 hi/lo (all three layers) ---------
// slot s = ((t*4+g)*F + c) holds W[t*32+g*8+j][c], j=0..7, as 8 bf16 (16 B).
template <int F>
__device__ __forceinline__ void splitW_one(const float* __restrict__ W,
                                           u16* __restrict__ Wh,
                                           u16* __restrict__ Wl, int s) {
    int c = s % F;
    int kb = (s / F) * 8;
    union { u32 u[4]; bf16x8 v; } hi, lo;
#pragma unroll
    for (int p = 0; p < 4; p++) {
        float x0 = W[(size_t)(kb + 2 * p) * F + c];
        float x1 = W[(size_t)(kb + 2 * p + 1) * F + c];
        u32 b0 = __float_as_uint(x0), b1 = __float_as_uint(x1);
        float l0 = x0 - __uint_as_float(b0 & 0xFFFF0000u);
        float l1 = x1 - __uint_as_float(b1 & 0xFFFF0000u);
        hi.u[p] = pack_hi16(b0, b1);
        lo.u[p] = pack_hi16(__float_as_uint(l0), __float_as_uint(l1));
    }
    *(bf16x8*)(Wh + (size_t)s * 8) = hi.v;
    *(bf16x8*)(Wl + (size_t)s * 8) = lo.v;
}

__global__ void k_splitW_all(const float* __restrict__ W1, u16* w1h, u16* w1l,
                             const float* __restrict__ W2, u16* w2h, u16* w2l,
                             const float* __restrict__ W3, u16* w3h, u16* w3l) {
    int s = blockIdx.x * 256 + threadIdx.x;
    if (s < 8192) splitW_one<128>(W1, w1h, w1l, s);               // 512x128/8
    else if (s < 9216) splitW_one<64>(W2, w2h, w2l, s - 8192);    // 128x64/8
    else if (s < 9728) splitW_one<64>(W3, w3h, w3l, s - 9216);    // 64x64/8
}

// --- MFMA GEMM: H'[N,F] = dinv_row * (X[N,K] @ W[K,F]), fp16 out -------------
// 128 thr = 2 waves (column halves); block tile 64 rows x F cols; grid 782.
// A K-tile [64][32] f32 double-buffered in LDS via global_load_lds (src
// chunk-swizzled c^=(row&7)); B direct global (L2-resident W splits).
template <int K, int F>
__global__ __launch_bounds__(128) void k_gemm_mfma(
        const float* __restrict__ X,
        const u16* __restrict__ Wh, const u16* __restrict__ Wl,
        const float* __restrict__ dinv, __half* __restrict__ Hh, int N) {
    constexpr int MF = 4;
    constexpr int NF = F / 32;         // 4 for F=128, 2 for F=64
    constexpr int NT = K / 32;         // K-steps
    __shared__ float4 smemA[2][512];   // 2 x 8 KB: [row][chunk] swizzled

    const int tid = threadIdx.x;
    const int lane = tid & 63;
    const int w = tid >> 6;            // 0..1 column half
    const int colbase = w * (NF * 16);
    const int lg = lane >> 4, li = lane & 15;
    const int row0 = blockIdx.x * 64;

    // stage K-tile t into buffer b: lds chunk c_lin=(j*128+tid) holds
    // X[row0 + c_lin>>3][t*32 + ((c_lin&7)^(row&7))*4 ..+3]
    auto stage = [&](int b, int t) {
#pragma unroll
        for (int j = 0; j < 4; j++) {
            int c_lin = j * 128 + tid;
            int row = c_lin >> 3, c = c_lin & 7;
            int rg = row0 + row;
            if (rg >= N) rg = N - 1;
            int cs = c ^ (row & 7);
            const float* g = X + (size_t)rg * K + t * 32 + cs * 4;
            // dest: wave-uniform base + lane*16 (m104)
            char* l = (char*)&smemA[b][0] + j * 2048 + w * 1024;
            __builtin_amdgcn_global_load_lds(
                (const __attribute__((address_space(1))) void*)g,
                (__attribute__((address_space(3))) void*)l, 16, 0, 0);
        }
    };

    f32x4 acc[MF][NF];
#pragma unroll
    for (int m = 0; m < MF; m++)
#pragma unroll
        for (int n = 0; n < NF; n++) acc[m][n] = (f32x4){0.f, 0.f, 0.f, 0.f};

    stage(0, 0);
    __syncthreads();

    for (int t = 0; t < NT; t++) {
        const int b = t & 1;
        // B(t) loads FIRST (their vmcnt wait must not drain the stage DMA)
        bf16x8 bh[NF], bl[NF];
        size_t slot0 = (size_t)(t * 4 + lg) * F + colbase + li;
#pragma unroll
        for (int n = 0; n < NF; n++) {
            bh[n] = *(const bf16x8*)(Wh + (slot0 + n * 16) * 8);
            bl[n] = *(const bf16x8*)(Wl + (slot0 + n * 16) * 8);
        }
        __builtin_amdgcn_sched_barrier(0);   // keep B issued before stage
        if (t + 1 < NT) stage(b ^ 1, t + 1); // async DMA, drained at barrier
        // A(t) fragments from LDS (swizzled b128 reads) -> split -> MFMA
        const float4* lt = &smemA[b][0];
        bf16x8 ah[MF], al[MF];
#pragma unroll
        for (int m = 0; m < MF; m++) {
            int row = m * 16 + li;
            int base = row * 8, sw = row & 7;
            float4 c0 = lt[base + ((2 * lg) ^ sw)];
            float4 c1 = lt[base + ((2 * lg + 1) ^ sw)];
            float xv[8] = {c0.x, c0.y, c0.z, c0.w, c1.x, c1.y, c1.z, c1.w};
            union { u32 u[4]; bf16x8 v; } hi, lo;
#pragma unroll
            for (int q = 0; q < 4; q++) {
                u32 b0 = __float_as_uint(xv[2 * q]);
                u32 b1 = __float_as_uint(xv[2 * q + 1]);
                float l0 = xv[2 * q]     - __uint_as_float(b0 & 0xFFFF0000u);
                float l1 = xv[2 * q + 1] - __uint_as_float(b1 & 0xFFFF0000u);
                hi.u[q] = pack_hi16(b0, b1);
                lo.u[q] = pack_hi16(__float_as_uint(l0), __float_as_uint(l1));
            }
            ah[m] = hi.v;
            al[m] = lo.v;
        }
        // 3-product accumulation: xh*wh + xh*wl + xl*wh
#pragma unroll
        for (int m = 0; m < MF; m++)
#pragma unroll
            for (int n = 0; n < NF; n++) {
                acc[m][n] = __builtin_amdgcn_mfma_f32_16x16x32_bf16(ah[m], bh[n], acc[m][n], 0, 0, 0);
                acc[m][n] = __builtin_amdgcn_mfma_f32_16x16x32_bf16(ah[m], bl[n], acc[m][n], 0, 0, 0);
                acc[m][n] = __builtin_amdgcn_mfma_f32_16x16x32_bf16(al[m], bh[n], acc[m][n], 0, 0, 0);
            }
        __syncthreads();   // drains stage(t+1) DMA + releases buf b for t+2
    }

    // C/D layout: col = lane&15, row = (lane>>4)*4 + reg (m89-verified)
    // Epilogue folds dinv[row] and converts to fp16.
#pragma unroll
    for (int m = 0; m < MF; m++) {
        int rb = row0 + m * 16 + lg * 4;
#pragma unroll
        for (int r = 0; r < 4; r++) {
            int gr = rb + r;
            if (gr >= N) continue;
            float di = dinv[gr];
#pragma unroll
            for (int n = 0; n < NF; n++) {
                int col = colbase + n * 16 + li;
                Hh[(size_t)gr * F + col] = __float2half(acc[m][n][r] * di);
            }
        }
    }
}

// --- aggregation, F=128, fp16 H' in, f32 out ---------------------------------
// y = act(dinv_d * (sum_s H'[s] + H'[d]) + b); one wave per node; 4-edge unroll.
template <bool RELU>
__global__ __launch_bounds__(256) void k_agg128(const __half* __restrict__ Hh,
                                                const int* __restrict__ offs,
                                                const int* __restrict__ csr,
                                                const float* __restrict__ dinv,
                                                const float* __restrict__ bias,
                                                float* __restrict__ Y, int N) {
    int node = blockIdx.x * 4 + (threadIdx.x >> 6);
    int lane = threadIdx.x & 63;
    if (node >= N) return;
    const __half2* H2 = (const __half2*)Hh;   // row = 64 half2
    float ax = 0.f, ay = 0.f;
    int o0 = offs[node], o1 = offs[node + 1];
    int e = o0;
    for (; e + 4 <= o1; e += 4) {
        int s0 = csr[e], s1 = csr[e + 1], s2 = csr[e + 2], s3 = csr[e + 3];
        __half2 v0 = H2[(size_t)s0 * 64 + lane];
        __half2 v1 = H2[(size_t)s1 * 64 + lane];
        __half2 v2 = H2[(size_t)s2 * 64 + lane];
        __half2 v3 = H2[(size_t)s3 * 64 + lane];
        float2 f0 = __half22float2(v0), f1 = __half22float2(v1);
        float2 f2 = __half22float2(v2), f3 = __half22float2(v3);
        ax += (f0.x + f1.x) + (f2.x + f3.x);
        ay += (f0.y + f1.y) + (f2.y + f3.y);
    }
    for (; e < o1; ++e) {
        float2 f0 = __half22float2(H2[(size_t)csr[e] * 64 + lane]);
        ax += f0.x; ay += f0.y;
    }
    float2 fs = __half22float2(H2[(size_t)node * 64 + lane]);
    float di = dinv[node];
    float2 bv = ((const float2*)bias)[lane];
    float vx = di * (ax + fs.x) + bv.x;
    float vy = di * (ay + fs.y) + bv.y;
    if (RELU) { vx = vx > 0.f ? vx : 0.2f * vx; vy = vy > 0.f ? vy : 0.2f * vy; }
    ((float2*)Y)[(size_t)node * 64 + lane] = make_float2(vx, vy);
}

// --- aggregation, F=64, fp16 H' in, f32 out ----------------------------------
// Half-wave (32 lanes) per node: fp16 row = 128 B = 32 x half2. 8 nodes/block.
template <bool RELU>
__global__ __launch_bounds__(256) void k_agg64(const __half* __restrict__ Hh,
                                               const int* __restrict__ offs,
                                               const int* __restrict__ csr,
                                               const float* __restrict__ dinv,
                                               const float* __restrict__ bias,
                                               float* __restrict__ Y, int N) {
    int node = blockIdx.x * 8 + (threadIdx.x >> 5);
    int lane = threadIdx.x & 31;
    if (node >= N) return;
    const __half2* H2 = (const __half2*)Hh;   // row = 32 half2
    float ax = 0.f, ay = 0.f;
    int o0 = offs[node], o1 = offs[node + 1];
    int e = o0;
    for (; e + 4 <= o1; e += 4) {
        int s0 = csr[e], s1 = csr[e + 1], s2 = csr[e + 2], s3 = csr[e + 3];
        float2 f0 = __half22float2(H2[(size_t)s0 * 32 + lane]);
        float2 f1 = __half22float2(H2[(size_t)s1 * 32 + lane]);
        float2 f2 = __half22float2(H2[(size_t)s2 * 32 + lane]);
        float2 f3 = __half22float2(H2[(size_t)s3 * 32 + lane]);
        ax += (f0.x + f1.x) + (f2.x + f3.x);
        ay += (f0.y + f1.y) + (f2.y + f3.y);
    }
    for (; e < o1; ++e) {
        float2 f0 = __half22float2(H2[(size_t)csr[e] * 32 + lane]);
        ax += f0.x; ay += f0.y;
    }
    float2 fs = __half22float2(H2[(size_t)node * 32 + lane]);
    float di = dinv[node];
    float2 bv = ((const float2*)bias)[lane];
    float vx = di * (ax + fs.x) + bv.x;
    float vy = di * (ay + fs.y) + bv.y;
    if (RELU) { vx = vx > 0.f ? vx : 0.2f * vx; vy = vy > 0.f ? vy : 0.2f * vy; }
    ((float2*)Y)[(size_t)node * 32 + lane] = make_float2(vx, vy);
}

extern "C" void kernel_launch(void* const* d_in, const int* in_sizes, int n_in,
                              void* d_out, int out_size, void* d_ws, size_t ws_size,
                              hipStream_t stream) {
    const float* x  = (const float*)d_in[0];
    const int*   ei = (const int*)d_in[1];
    const float* W1 = (const float*)d_in[2];
    const float* b1 = (const float*)d_in[3];
    const float* W2 = (const float*)d_in[4];
    const float* b2 = (const float*)d_in[5];
    const float* W3 = (const float*)d_in[6];
    const float* b3 = (const float*)d_in[7];

    const int N = in_sizes[0] / 512;
    const int E = in_sizes[1] / 2;
    const int nb = (N + 255) / 256;

    char* w = (char*)d_ws;
    auto take = [&](size_t bytes) -> char* {
        char* p = w;
        w += alignup(bytes, 256);
        return p;
    };
    int*    flag  = (int*)take(256);
    int*    deg   = (int*)take((size_t)N * 4);
    int*    offs  = (int*)take((size_t)(N + 1) * 4);
    int*    bsums = (int*)take((size_t)nb * 4);
    int*    csr   = (int*)take((size_t)E * 4);
    float*  dinv  = (float*)take((size_t)N * 4);
    __half* bufA  = (__half*)take((size_t)N * 128 * 2);   // H' fp16
    float*  bufB  = (float*)take((size_t)N * 128 * 4);    // agg out f32
    u16*    w1h   = (u16*)take((size_t)512 * 128 * 2);
    u16*    w1l   = (u16*)take((size_t)512 * 128 * 2);
    u16*    w2h   = (u16*)take((size_t)128 * 64 * 2);
    u16*    w2l   = (u16*)take((size_t)128 * 64 * 2);
    u16*    w3h   = (u16*)take((size_t)64 * 64 * 2);
    u16*    w3l   = (u16*)take((size_t)64 * 64 * 2);

    const int TB = 256;
    // preprocessing (6 launches)
    k_init<<<(N + TB - 1) / TB, TB, 0, stream>>>(ei, flag, deg, N);
    k_deg<<<(E + TB - 1) / TB, TB, 0, stream>>>(ei, E, flag, deg);
    k_scan1<<<nb, 256, 0, stream>>>(deg, offs, bsums, dinv, N);
    k_scan23<<<nb, 256, 0, stream>>>(offs, bsums, nb, N, E);
    k_fill<<<(E + TB - 1) / TB, TB, 0, stream>>>(ei, E, flag, offs, deg, csr);
    k_splitW_all<<<(9728 + 255) / 256, 256, 0, stream>>>(W1, w1h, w1l,
                                                         W2, w2h, w2l,
                                                         W3, w3h, w3l);

    const int gemm_grid = (N + 63) / 64;
    // layer 1
    k_gemm_mfma<512, 128><<<gemm_grid, 128, 0, stream>>>(x, w1h, w1l, dinv, bufA, N);
    k_agg128<true><<<(N + 3) / 4, 256, 0, stream>>>(bufA, offs, csr, dinv, b1, bufB, N);
    // layer 2
    k_gemm_mfma<128, 64><<<gemm_grid, 128, 0, stream>>>(bufB, w2h, w2l, dinv, bufA, N);
    k_agg64<true><<<(N + 7) / 8, 256, 0, stream>>>(bufA, offs, csr, dinv, b2, bufB, N);
    // layer 3 (no relu), write straight to output
    k_gemm_mfma<64, 64><<<gemm_grid, 128, 0, stream>>>(bufB, w3h, w3l, dinv, bufA, N);
    k_agg64<false><<<(N + 7) / 8, 256, 0, stream>>>(bufA, offs, csr, dinv, b3,
                                                    (float*)d_out, N);
}